// Round 5
// baseline (157.747 us; speedup 1.0000x reference)
//
#include <hip/hip_runtime.h>
#include <hip/hip_bf16.h>
#include <stdint.h>

#define SEQ 2048
#define HD  128
#define WIN 512
#define NH  16
#define NKV 4
#define BATCH 2

typedef __attribute__((ext_vector_type(8))) short bf16x8;
typedef __attribute__((ext_vector_type(4))) short bf16x4;
typedef __attribute__((ext_vector_type(4))) float f32x4;
typedef __attribute__((ext_vector_type(4))) uint32_t u32x4;
typedef __attribute__((ext_vector_type(2))) uint32_t u32x2;

// v_exp_f32: D = 2^S0 — avoids the glibc __exp2f macro collision
#define EXP2(x) __builtin_amdgcn_exp2f(x)

// LDS row strides in bf16 elements (byte-strides multiples of 16B for b128)
#define KSTR 136   // K tile  [64 keys][128 dims]
#define VSTR 72    // V^T tile [128 dims][64 keys]

__device__ __forceinline__ uint32_t pk2(float a, float b) {
    __hip_bfloat162 h = __float22bfloat162_rn(make_float2(a, b));
    return *reinterpret_cast<uint32_t*>(&h);
}

// 8 waves/block (512 thr), 16 queries/wave -> 16 waves/CU resident (vs 8),
// the main latency-hiding lever. S^T = K·Q^T so softmax stats are per-column
// (q = lane&15). K/V double-buffered in LDS -> single barrier per tile.
// P stays in registers; PV uses 16x16x32 MFMA with a permuted k-mapping
// (k-reduction is order-invariant: A/B just need the same key<->slot map),
// so PV is 16 K=32 MFMAs instead of 32 K=16.
__global__ __launch_bounds__(512) __attribute__((amdgpu_waves_per_eu(4, 4)))
void fa_mfma(
    const float* __restrict__ q,
    const float* __restrict__ k,
    const float* __restrict__ v,
    float* __restrict__ out)
{
    const int tid  = threadIdx.x;
    const int wave = tid >> 6;             // 0..7
    const int lane = tid & 63;
    const int l4   = lane >> 4;
    const int l15  = lane & 15;

    const int bh   = blockIdx.x >> 4;      // b*NH + h
    const int qblk = blockIdx.x & 15;
    const int q0   = qblk << 7;            // 128 queries per block
    const int hkv  = (bh & (NH - 1)) >> 2; // G = 4
    const int b    = bh >> 4;

    const int i0   = q0 + wave * 16;       // wave's first query row

    __shared__ __align__(16) uint16_t lds_k[2][64 * KSTR];
    __shared__ __align__(16) uint16_t lds_vt[2][HD * VSTR];

    // scale * log2(e): softmax computed in exp2 domain
    const float scale2 = 0.08838834764831845f * 1.4426950408889634f;

    const size_t qbase  = (size_t)bh * SEQ * HD;
    const size_t kvbase = (size_t)(b * NKV + hkv) * SEQ * HD;

    // ---- preload Q fragments (B-operand: B[k=dim][n=q], q = l15) ----
    bf16x8 qf[4];
    {
        const float* qr = q + qbase + (size_t)(i0 + l15) * HD;
        #pragma unroll
        for (int ks = 0; ks < 4; ++ks) {
            const float4* g = reinterpret_cast<const float4*>(qr + ks * 32 + l4 * 8);
            float4 a = g[0], bq = g[1];
            u32x4 t;
            t.x = pk2(a.x * scale2, a.y * scale2);
            t.y = pk2(a.z * scale2, a.w * scale2);
            t.z = pk2(bq.x * scale2, bq.y * scale2);
            t.w = pk2(bq.z * scale2, bq.w * scale2);
            qf[ks] = __builtin_bit_cast(bf16x8, t);
        }
    }

    f32x4 O[8];
    #pragma unroll
    for (int a2 = 0; a2 < 8; ++a2) O[a2] = (f32x4){0.f, 0.f, 0.f, 0.f};
    float mrow = -1e30f;
    float lrow = 0.f;

    const int kt_lo_blk = (q0 >= 512) ? ((q0 - 511) >> 6) : 0;
    const int kt_hi_blk = (q0 + 127) >> 6;
    const int lo_w = (i0 >= 512) ? ((i0 - 511) >> 6) : 0;
    const int hi_w = (i0 + 15) >> 6;

    // ---- prefetch registers (512-thread staging split) ----
    const int vdg = tid & 31;   // dim group (4 dims)
    const int vkg = tid >> 5;   // key group (4 keys), 0..15
    float4 rKa[2], rKb[2], rV[4];

    auto prefetch_k = [&](int kt) {
        const float* kp = k + kvbase + (size_t)kt * 64 * HD;
        #pragma unroll
        for (int it = 0; it < 2; ++it) {
            int flat8 = tid + it * 512, key = flat8 >> 4, ch = flat8 & 15;
            const float4* g = reinterpret_cast<const float4*>(kp + key * HD + ch * 8);
            rKa[it] = g[0]; rKb[it] = g[1];
        }
    };
    auto prefetch_v = [&](int kt) {
        const float* vp = v + kvbase + (size_t)kt * 64 * HD;
        #pragma unroll
        for (int r = 0; r < 4; ++r)
            rV[r] = *reinterpret_cast<const float4*>(vp + (vkg * 4 + r) * HD + vdg * 4);
    };

    auto pack_k = [&](int pb) {
        #pragma unroll
        for (int it = 0; it < 2; ++it) {
            int flat8 = tid + it * 512, key = flat8 >> 4, ch = flat8 & 15;
            uint4 wv;
            wv.x = pk2(rKa[it].x, rKa[it].y);  wv.y = pk2(rKa[it].z, rKa[it].w);
            wv.z = pk2(rKb[it].x, rKb[it].y);  wv.w = pk2(rKb[it].z, rKb[it].w);
            *reinterpret_cast<uint4*>(&lds_k[pb][key * KSTR + ch * 8]) = wv;
        }
    };
    auto pack_v = [&](int pb) {
        // V (register 4x4 transpose) -> LDS, b64 per dim-row
        const float* rvf = reinterpret_cast<const float*>(rV);
        #pragma unroll
        for (int i = 0; i < 4; ++i) {
            u32x2 wv;
            wv.x = pk2(rvf[0 * 4 + i], rvf[1 * 4 + i]);
            wv.y = pk2(rvf[2 * 4 + i], rvf[3 * 4 + i]);
            *reinterpret_cast<u32x2*>(&lds_vt[pb][(vdg * 4 + i) * VSTR + vkg * 4]) = wv;
        }
    };

    prefetch_k(kt_lo_blk);
    prefetch_v(kt_lo_blk);
    pack_k(0);
    pack_v(0);
    __syncthreads();

    int par = 0;
    for (int kt = kt_lo_blk; kt <= kt_hi_blk; ++kt) {
        const bool more = (kt < kt_hi_blk);
        if (more) prefetch_k(kt + 1);   // K loads early; V loads after pack_k

        if (kt >= lo_w && kt <= hi_w) {
            // ---------- S^T = K · Q^T (16 MFMAs, K=32) ----------
            f32x4 sf[4];
            #pragma unroll
            for (int mt = 0; mt < 4; ++mt) sf[mt] = (f32x4){0.f, 0.f, 0.f, 0.f};
            __builtin_amdgcn_s_setprio(1);
            #pragma unroll
            for (int mt = 0; mt < 4; ++mt) {
                #pragma unroll
                for (int ks = 0; ks < 4; ++ks) {
                    bf16x8 af = *reinterpret_cast<const bf16x8*>(
                        &lds_k[par][(mt * 16 + l15) * KSTR + ks * 32 + l4 * 8]);
                    sf[mt] = __builtin_amdgcn_mfma_f32_16x16x32_bf16(
                        af, qf[ks], sf[mt], 0, 0, 0);
                }
            }
            __builtin_amdgcn_s_setprio(0);
            // ---- pack next K tile (frees rKa/rKb), then issue V loads ------
            if (more) { pack_k(par ^ 1); prefetch_v(kt + 1); }
            // ---------- mask (first/window and last/causal tiles only) ------
            const bool needmask = (kt == hi_w) || (kt == lo_w && i0 > 511);
            if (needmask) {
                const int iq = i0 + l15;
                #pragma unroll
                for (int mt = 0; mt < 4; ++mt) {
                    int jb = kt * 64 + mt * 16 + l4 * 4;
                    #pragma unroll
                    for (int r = 0; r < 4; ++r) {
                        int j = jb + r;
                        if (!((j <= iq) && (iq - j < WIN))) sf[mt][r] = -1e30f;
                    }
                }
            }
            // ---------- online softmax, exp2 domain, defer-max (THR=8) ------
            float a0 = fmaxf(fmaxf(sf[0][0], sf[0][1]), fmaxf(sf[0][2], sf[0][3]));
            float a1 = fmaxf(fmaxf(sf[1][0], sf[1][1]), fmaxf(sf[1][2], sf[1][3]));
            float a2 = fmaxf(fmaxf(sf[2][0], sf[2][1]), fmaxf(sf[2][2], sf[2][3]));
            float a3 = fmaxf(fmaxf(sf[3][0], sf[3][1]), fmaxf(sf[3][2], sf[3][3]));
            float tm = fmaxf(fmaxf(a0, a1), fmaxf(a2, a3));
            tm = fmaxf(tm, __shfl_xor(tm, 16, 64));
            tm = fmaxf(tm, __shfl_xor(tm, 32, 64));
            const bool defer = __all(tm <= mrow + 8.0f);
            if (!defer) {
                float mn = fmaxf(mrow, tm);
                float alpha = EXP2(mrow - mn);
                mrow = mn;
                lrow *= alpha;
                #pragma unroll
                for (int r = 0; r < 4; ++r) {
                    float ar = __shfl(alpha, l4 * 4 + r, 64);
                    #pragma unroll
                    for (int nt = 0; nt < 8; ++nt) O[nt][r] *= ar;
                }
            }
            // ---------- P in registers (bf16 pairs), per-column sums --------
            bf16x4 pfrag[4];
            {
                float me = fmaxf(mrow, -1e20f);   // fully-masked rows -> p = 0
                float s[4];
                #pragma unroll
                for (int mt = 0; mt < 4; ++mt) {
                    float p0 = EXP2(sf[mt][0] - me);
                    float p1 = EXP2(sf[mt][1] - me);
                    float p2 = EXP2(sf[mt][2] - me);
                    float p3 = EXP2(sf[mt][3] - me);
                    u32x2 t;
                    t.x = pk2(p0, p1);
                    t.y = pk2(p2, p3);
                    pfrag[mt] = __builtin_bit_cast(bf16x4, t);
                    s[mt] = (p0 + p1) + (p2 + p3);
                }
                float ts = (s[0] + s[1]) + (s[2] + s[3]);
                ts += __shfl_xor(ts, 16, 64);
                ts += __shfl_xor(ts, 32, 64);
                lrow += ts;
            }
            // ---- pack next V tile (frees rV; overlaps with PV issue) -------
            if (more) pack_v(par ^ 1);
            // ---------- O += P · V  (16 MFMAs, K=32, permuted k-map) --------
            // Slot map for pair s: j0..3 = keys s*32+l4*4+j, j4..7 = +16.
            // Valid because MFMA's k-reduction is invariant to the slot->key
            // bijection as long as A and B use the same map.
            __builtin_amdgcn_s_setprio(1);
            #pragma unroll
            for (int s = 0; s < 2; ++s) {
                bf16x8 pa = __builtin_shufflevector(pfrag[2 * s], pfrag[2 * s + 1],
                                                    0, 1, 2, 3, 4, 5, 6, 7);
                #pragma unroll
                for (int nt = 0; nt < 8; ++nt) {
                    const uint16_t* vrow = &lds_vt[par][(nt * 16 + l15) * VSTR];
                    bf16x4 v0 = *reinterpret_cast<const bf16x4*>(vrow + s * 32 + l4 * 4);
                    bf16x4 v1 = *reinterpret_cast<const bf16x4*>(vrow + s * 32 + 16 + l4 * 4);
                    bf16x8 vf = __builtin_shufflevector(v0, v1, 0, 1, 2, 3, 4, 5, 6, 7);
                    O[nt] = __builtin_amdgcn_mfma_f32_16x16x32_bf16(pa, vf, O[nt], 0, 0, 0);
                }
            }
            __builtin_amdgcn_s_setprio(0);
        } else {
            if (more) { prefetch_v(kt + 1); pack_k(par ^ 1); pack_v(par ^ 1); }
        }
        __syncthreads();
        par ^= 1;
    }

    // ---------- epilogue: O / l, f32 out ----------
    {
        float inv = 1.0f / lrow;
        #pragma unroll
        for (int r = 0; r < 4; ++r) {
            float li = __shfl(inv, l4 * 4 + r, 64);
            int row = i0 + l4 * 4 + r;
            float* orow = out + qbase + (size_t)row * HD;
            #pragma unroll
            for (int nt = 0; nt < 8; ++nt)
                orow[nt * 16 + l15] = O[nt][r] * li;
        }
    }
}

extern "C" void kernel_launch(void* const* d_in, const int* in_sizes, int n_in,
                              void* d_out, int out_size, void* d_ws, size_t ws_size,
                              hipStream_t stream) {
    const float* q = (const float*)d_in[0];
    const float* k = (const float*)d_in[1];
    const float* v = (const float*)d_in[2];
    float* out     = (float*)d_out;

    hipLaunchKernelGGL(fa_mfma, dim3(BATCH * NH * (SEQ / 128)), dim3(512), 0, stream,
                       q, k, v, out);
}

// Round 6
// 143.504 us; speedup vs baseline: 1.0993x; 1.0993x over previous
//
#include <hip/hip_runtime.h>
#include <hip/hip_bf16.h>
#include <stdint.h>

#define SEQ 2048
#define HD  128
#define WIN 512
#define NH  16
#define NKV 4
#define BATCH 2

typedef __attribute__((ext_vector_type(8))) short bf16x8;
typedef __attribute__((ext_vector_type(4))) short bf16x4;
typedef __attribute__((ext_vector_type(4))) float f32x4;
typedef __attribute__((ext_vector_type(4))) uint32_t u32x4;
typedef __attribute__((ext_vector_type(2))) uint32_t u32x2;

// v_exp_f32: D = 2^S0 — avoids the glibc __exp2f macro collision
#define EXP2(x) __builtin_amdgcn_exp2f(x)

// LDS row strides in bf16 elements
#define KSTR 136   // K tile [64 keys][128 dims] (16B-multiple rows for b128)
#define VSTR 72    // V^T base stride [128 dims][64 keys]
// V^T row skew: +4 elements per 4-row group. Without it the pack_v write
// bank = (16*vdg + ...) mod 32 collapses 32 lanes onto 2 bank-starts
// (16-way conflict, ~5.7x). With skew: stride/4-rows = 146 words,
// 146 mod 32 = 18, gcd(18,32)=2 -> 16 spread starts (~4-way write, 2-way read).
#define VT_ROWS (HD * VSTR + (HD / 4) * 4)
__device__ __forceinline__ int vt_off(int row, int col) {
    return row * VSTR + (row >> 2) * 4 + col;
}

__device__ __forceinline__ uint32_t pk2(float a, float b) {
    __hip_bfloat162 h = __float22bfloat162_rn(make_float2(a, b));
    return *reinterpret_cast<uint32_t*>(&h);
}

// 8 waves/block (512 thr), 16 queries/wave -> 16 waves/CU resident,
// the main latency-hiding lever (round 5: occupancy 16->31%).
// S^T = K·Q^T so softmax stats are per-column (q = lane&15).
// K/V double-buffered in LDS -> single barrier per tile. P stays in
// registers; PV uses 16x16x32 MFMA with a permuted k-mapping.
//
// Register policy: peak live ~105 VGPRs. launch_bounds(512, 2) keeps the
// VGPR cap at 256 and lets the backend pick its natural ~128.
// waves_per_eu(4,4) made it allocate 64 and spill ~64 MB/dispatch (round 5:
// WRITE_SIZE 100 MB vs 36 ideal) — do NOT pin waves/EU here.
__global__ __launch_bounds__(512, 2)
void fa_mfma(
    const float* __restrict__ q,
    const float* __restrict__ k,
    const float* __restrict__ v,
    float* __restrict__ out)
{
    const int tid  = threadIdx.x;
    const int wave = tid >> 6;             // 0..7
    const int lane = tid & 63;
    const int l4   = lane >> 4;
    const int l15  = lane & 15;

    const int bh   = blockIdx.x >> 4;      // b*NH + h
    const int qblk = blockIdx.x & 15;
    const int q0   = qblk << 7;            // 128 queries per block
    const int hkv  = (bh & (NH - 1)) >> 2; // G = 4
    const int b    = bh >> 4;

    const int i0   = q0 + wave * 16;       // wave's first query row

    __shared__ __align__(16) uint16_t lds_k[2][64 * KSTR];
    __shared__ __align__(16) uint16_t lds_vt[2][VT_ROWS];

    // scale * log2(e): softmax computed in exp2 domain
    const float scale2 = 0.08838834764831845f * 1.4426950408889634f;

    const size_t qbase  = (size_t)bh * SEQ * HD;
    const size_t kvbase = (size_t)(b * NKV + hkv) * SEQ * HD;

    // ---- preload Q fragments (B-operand: B[k=dim][n=q], q = l15) ----
    bf16x8 qf[4];
    {
        const float* qr = q + qbase + (size_t)(i0 + l15) * HD;
        #pragma unroll
        for (int ks = 0; ks < 4; ++ks) {
            const float4* g = reinterpret_cast<const float4*>(qr + ks * 32 + l4 * 8);
            float4 a = g[0], bq = g[1];
            u32x4 t;
            t.x = pk2(a.x * scale2, a.y * scale2);
            t.y = pk2(a.z * scale2, a.w * scale2);
            t.z = pk2(bq.x * scale2, bq.y * scale2);
            t.w = pk2(bq.z * scale2, bq.w * scale2);
            qf[ks] = __builtin_bit_cast(bf16x8, t);
        }
    }

    f32x4 O[8];
    #pragma unroll
    for (int a2 = 0; a2 < 8; ++a2) O[a2] = (f32x4){0.f, 0.f, 0.f, 0.f};
    float mrow = -1e30f;
    float lrow = 0.f;

    const int kt_lo_blk = (q0 >= 512) ? ((q0 - 511) >> 6) : 0;
    const int kt_hi_blk = (q0 + 127) >> 6;
    const int lo_w = (i0 >= 512) ? ((i0 - 511) >> 6) : 0;
    const int hi_w = (i0 + 15) >> 6;

    // ---- prefetch registers (512-thread staging split) ----
    const int vdg = tid & 31;   // dim group (4 dims)
    const int vkg = tid >> 5;   // key group (4 keys), 0..15
    float4 rKa[2], rKb[2], rV[4];

    auto prefetch_k = [&](int kt) {
        const float* kp = k + kvbase + (size_t)kt * 64 * HD;
        #pragma unroll
        for (int it = 0; it < 2; ++it) {
            int flat8 = tid + it * 512, key = flat8 >> 4, ch = flat8 & 15;
            const float4* g = reinterpret_cast<const float4*>(kp + key * HD + ch * 8);
            rKa[it] = g[0]; rKb[it] = g[1];
        }
    };
    auto prefetch_v = [&](int kt) {
        const float* vp = v + kvbase + (size_t)kt * 64 * HD;
        #pragma unroll
        for (int r = 0; r < 4; ++r)
            rV[r] = *reinterpret_cast<const float4*>(vp + (vkg * 4 + r) * HD + vdg * 4);
    };

    auto pack_k = [&](int pb) {
        #pragma unroll
        for (int it = 0; it < 2; ++it) {
            int flat8 = tid + it * 512, key = flat8 >> 4, ch = flat8 & 15;
            uint4 wv;
            wv.x = pk2(rKa[it].x, rKa[it].y);  wv.y = pk2(rKa[it].z, rKa[it].w);
            wv.z = pk2(rKb[it].x, rKb[it].y);  wv.w = pk2(rKb[it].z, rKb[it].w);
            *reinterpret_cast<uint4*>(&lds_k[pb][key * KSTR + ch * 8]) = wv;
        }
    };
    auto pack_v = [&](int pb) {
        // V (register 4x4 transpose) -> LDS, b64 per dim-row, skewed layout
        const float* rvf = reinterpret_cast<const float*>(rV);
        #pragma unroll
        for (int i = 0; i < 4; ++i) {
            u32x2 wv;
            wv.x = pk2(rvf[0 * 4 + i], rvf[1 * 4 + i]);
            wv.y = pk2(rvf[2 * 4 + i], rvf[3 * 4 + i]);
            *reinterpret_cast<u32x2*>(&lds_vt[pb][vt_off(vdg * 4 + i, vkg * 4)]) = wv;
        }
    };

    prefetch_k(kt_lo_blk);
    prefetch_v(kt_lo_blk);
    pack_k(0);
    pack_v(0);
    __syncthreads();

    int par = 0;
    for (int kt = kt_lo_blk; kt <= kt_hi_blk; ++kt) {
        const bool more = (kt < kt_hi_blk);
        if (more) prefetch_k(kt + 1);   // K loads early; V loads after pack_k

        if (kt >= lo_w && kt <= hi_w) {
            // ---------- S^T = K · Q^T (16 MFMAs, K=32) ----------
            f32x4 sf[4];
            #pragma unroll
            for (int mt = 0; mt < 4; ++mt) sf[mt] = (f32x4){0.f, 0.f, 0.f, 0.f};
            __builtin_amdgcn_s_setprio(1);
            #pragma unroll
            for (int mt = 0; mt < 4; ++mt) {
                #pragma unroll
                for (int ks = 0; ks < 4; ++ks) {
                    bf16x8 af = *reinterpret_cast<const bf16x8*>(
                        &lds_k[par][(mt * 16 + l15) * KSTR + ks * 32 + l4 * 8]);
                    sf[mt] = __builtin_amdgcn_mfma_f32_16x16x32_bf16(
                        af, qf[ks], sf[mt], 0, 0, 0);
                }
            }
            __builtin_amdgcn_s_setprio(0);
            // ---- pack next K tile (frees rKa/rKb), then issue V loads ------
            if (more) { pack_k(par ^ 1); prefetch_v(kt + 1); }
            // ---------- mask (first/window and last/causal tiles only) ------
            const bool needmask = (kt == hi_w) || (kt == lo_w && i0 > 511);
            if (needmask) {
                const int iq = i0 + l15;
                #pragma unroll
                for (int mt = 0; mt < 4; ++mt) {
                    int jb = kt * 64 + mt * 16 + l4 * 4;
                    #pragma unroll
                    for (int r = 0; r < 4; ++r) {
                        int j = jb + r;
                        if (!((j <= iq) && (iq - j < WIN))) sf[mt][r] = -1e30f;
                    }
                }
            }
            // ---------- online softmax, exp2 domain, defer-max (THR=8) ------
            float a0 = fmaxf(fmaxf(sf[0][0], sf[0][1]), fmaxf(sf[0][2], sf[0][3]));
            float a1 = fmaxf(fmaxf(sf[1][0], sf[1][1]), fmaxf(sf[1][2], sf[1][3]));
            float a2 = fmaxf(fmaxf(sf[2][0], sf[2][1]), fmaxf(sf[2][2], sf[2][3]));
            float a3 = fmaxf(fmaxf(sf[3][0], sf[3][1]), fmaxf(sf[3][2], sf[3][3]));
            float tm = fmaxf(fmaxf(a0, a1), fmaxf(a2, a3));
            tm = fmaxf(tm, __shfl_xor(tm, 16, 64));
            tm = fmaxf(tm, __shfl_xor(tm, 32, 64));
            const bool defer = __all(tm <= mrow + 8.0f);
            if (!defer) {
                float mn = fmaxf(mrow, tm);
                float alpha = EXP2(mrow - mn);
                mrow = mn;
                lrow *= alpha;
                #pragma unroll
                for (int r = 0; r < 4; ++r) {
                    float ar = __shfl(alpha, l4 * 4 + r, 64);
                    #pragma unroll
                    for (int nt = 0; nt < 8; ++nt) O[nt][r] *= ar;
                }
            }
            // ---------- P in registers (bf16 pairs), per-column sums --------
            bf16x4 pfrag[4];
            {
                float me = fmaxf(mrow, -1e20f);   // fully-masked rows -> p = 0
                float s[4];
                #pragma unroll
                for (int mt = 0; mt < 4; ++mt) {
                    float p0 = EXP2(sf[mt][0] - me);
                    float p1 = EXP2(sf[mt][1] - me);
                    float p2 = EXP2(sf[mt][2] - me);
                    float p3 = EXP2(sf[mt][3] - me);
                    u32x2 t;
                    t.x = pk2(p0, p1);
                    t.y = pk2(p2, p3);
                    pfrag[mt] = __builtin_bit_cast(bf16x4, t);
                    s[mt] = (p0 + p1) + (p2 + p3);
                }
                float ts = (s[0] + s[1]) + (s[2] + s[3]);
                ts += __shfl_xor(ts, 16, 64);
                ts += __shfl_xor(ts, 32, 64);
                lrow += ts;
            }
            // ---- pack next V tile (frees rV; overlaps with PV issue) -------
            if (more) pack_v(par ^ 1);
            // ---------- O += P · V  (16 MFMAs, K=32, permuted k-map) --------
            // Slot map for pair s: j0..3 = keys s*32+l4*4+j, j4..7 = +16.
            // Valid because MFMA's k-reduction is invariant to the slot->key
            // bijection as long as A and B use the same map.
            __builtin_amdgcn_s_setprio(1);
            #pragma unroll
            for (int s = 0; s < 2; ++s) {
                bf16x8 pa = __builtin_shufflevector(pfrag[2 * s], pfrag[2 * s + 1],
                                                    0, 1, 2, 3, 4, 5, 6, 7);
                #pragma unroll
                for (int nt = 0; nt < 8; ++nt) {
                    const int vr = nt * 16 + l15;
                    bf16x4 v0 = *reinterpret_cast<const bf16x4*>(
                        &lds_vt[par][vt_off(vr, s * 32 + l4 * 4)]);
                    bf16x4 v1 = *reinterpret_cast<const bf16x4*>(
                        &lds_vt[par][vt_off(vr, s * 32 + 16 + l4 * 4)]);
                    bf16x8 vf = __builtin_shufflevector(v0, v1, 0, 1, 2, 3, 4, 5, 6, 7);
                    O[nt] = __builtin_amdgcn_mfma_f32_16x16x32_bf16(pa, vf, O[nt], 0, 0, 0);
                }
            }
            __builtin_amdgcn_s_setprio(0);
        } else {
            if (more) { prefetch_v(kt + 1); pack_k(par ^ 1); pack_v(par ^ 1); }
        }
        __syncthreads();
        par ^= 1;
    }

    // ---------- epilogue: O / l, f32 out ----------
    {
        float inv = 1.0f / lrow;
        #pragma unroll
        for (int r = 0; r < 4; ++r) {
            float li = __shfl(inv, l4 * 4 + r, 64);
            int row = i0 + l4 * 4 + r;
            float* orow = out + qbase + (size_t)row * HD;
            #pragma unroll
            for (int nt = 0; nt < 8; ++nt)
                orow[nt * 16 + l15] = O[nt][r] * li;
        }
    }
}

extern "C" void kernel_launch(void* const* d_in, const int* in_sizes, int n_in,
                              void* d_out, int out_size, void* d_ws, size_t ws_size,
                              hipStream_t stream) {
    const float* q = (const float*)d_in[0];
    const float* k = (const float*)d_in[1];
    const float* v = (const float*)d_in[2];
    float* out     = (float*)d_out;

    hipLaunchKernelGGL(fa_mfma, dim3(BATCH * NH * (SEQ / 128)), dim3(512), 0, stream,
                       q, k, v, out);
}

// Round 8
// 120.988 us; speedup vs baseline: 1.3038x; 1.1861x over previous
//
#include <hip/hip_runtime.h>
#include <hip/hip_bf16.h>
#include <stdint.h>

#define SEQ 2048
#define HD  128
#define WIN 512
#define NH  16
#define NKV 4
#define BATCH 2

typedef __attribute__((ext_vector_type(8))) short bf16x8;
typedef __attribute__((ext_vector_type(4))) short bf16x4;
typedef __attribute__((ext_vector_type(4))) float f32x4;
typedef __attribute__((ext_vector_type(4))) uint32_t u32x4;
typedef __attribute__((ext_vector_type(2))) uint32_t u32x2;

// v_exp_f32: D = 2^S0 — avoids the glibc __exp2f macro collision
#define EXP2(x) __builtin_amdgcn_exp2f(x)

#define AS1(p) ((const __attribute__((address_space(1))) uint32_t*)(p))
#define AS3(p) ((__attribute__((address_space(3))) uint32_t*)(p))

__device__ __forceinline__ uint32_t pk2(float a, float b) {
    __hip_bfloat162 h = __float22bfloat162_rn(make_float2(a, b));
    return *reinterpret_cast<uint32_t*>(&h);
}

// ---------------------------------------------------------------------------
// Prep kernel: one block per (b*NKV+hkv, kt) 64-key tile.
//  K -> bf16, row-major [s][128] with 16B-slot XOR swizzle baked in:
//       elem(row,col) = row*128 + ((col>>3) ^ (row&7))*8 + (col&7)
//  V -> bf16 V^T per tile: [dim][64 keys] with key-permutation
//       keypos(key): s=key>>5, h=(key>>4)&1, u=key&15 -> s*32 + (u>>2)*8 + h*4 + (u&3)
//       (makes each PV B-fragment one contiguous b128) + same 8-elem XOR swizzle.
// Main kernel then stages both via linear global_load_lds (rule #21: linear
// LDS dest + pre-swizzled global source + swizzled LDS reads).
// ---------------------------------------------------------------------------
__global__ __launch_bounds__(256) void prep_kv(
    const float* __restrict__ k,
    const float* __restrict__ v,
    uint16_t* __restrict__ kb,   // [8][2048][128]
    uint16_t* __restrict__ vt)   // [8][32][8192]
{
    const int tile = blockIdx.x;        // (kvh*32 + kt)
    const int kvh  = tile >> 5;
    const int kt   = tile & 31;
    const int t    = threadIdx.x;

    const float* ksrc = k + ((size_t)kvh * SEQ + kt * 64) * HD;
    const float* vsrc = v + ((size_t)kvh * SEQ + kt * 64) * HD;
    uint16_t* kdst = kb + ((size_t)kvh * SEQ + kt * 64) * HD;
    uint16_t* vdst = vt + ((size_t)kvh * 32 + kt) * (size_t)(64 * HD);

    __shared__ uint16_t lv[64][132];   // V tile bf16 (padded rows)

    // stage V tile to LDS as bf16 (coalesced float4 reads)
    #pragma unroll
    for (int i = 0; i < 8; ++i) {
        int u = t + i * 256;            // 2048 float4-units
        int row = u >> 5, c4 = u & 31;
        float4 f = *reinterpret_cast<const float4*>(vsrc + row * HD + c4 * 4);
        u32x2 w; w.x = pk2(f.x, f.y); w.y = pk2(f.z, f.w);
        *reinterpret_cast<u32x2*>(&lv[row][c4 * 4]) = w;
    }
    // K: swizzled row copy (no transpose)
    #pragma unroll
    for (int i = 0; i < 8; ++i) {
        int u = t + i * 256;
        int row = u >> 5, c4 = u & 31;
        float4 f = *reinterpret_cast<const float4*>(ksrc + row * HD + c4 * 4);
        u32x2 w; w.x = pk2(f.x, f.y); w.y = pk2(f.z, f.w);
        int col = c4 * 4;
        int e = row * HD + ((((col >> 3) ^ (row & 7)) << 3) | (col & 7));
        *reinterpret_cast<u32x2*>(&kdst[e]) = w;
    }
    __syncthreads();
    // V^T readout: key-perm + group XOR swizzle, coalesced 16B writes
    #pragma unroll
    for (int i = 0; i < 4; ++i) {
        int g = t + i * 256;            // 1024 granules: dim = g>>3, pg = g&7
        int dim = g >> 3, pg = g & 7;
        uint32_t w[4];
        #pragma unroll
        for (int jj = 0; jj < 4; ++jj) {
            int p0 = pg * 8 + jj * 2;
            // invert keypos: p -> key
            int s0 = p0 >> 5, w0 = p0 & 31;
            int key0 = s0 * 32 + ((w0 >> 2) & 1) * 16 + (w0 >> 3) * 4 + (w0 & 3);
            int p1 = p0 + 1;
            int s1 = p1 >> 5, w1 = p1 & 31;
            int key1 = s1 * 32 + ((w1 >> 2) & 1) * 16 + (w1 >> 3) * 4 + (w1 & 3);
            w[jj] = (uint32_t)lv[key0][dim] | ((uint32_t)lv[key1][dim] << 16);
        }
        int e = dim * 64 + ((pg ^ (dim & 7)) << 3);
        u32x4 wv = {w[0], w[1], w[2], w[3]};
        *reinterpret_cast<u32x4*>(&vdst[e]) = wv;
    }
}

// ---------------------------------------------------------------------------
// Main: 8 waves/block (512 thr), 16 q/wave, K/V double-buffered in LDS via
// global_load_lds DMA (no staging registers, no pack VALU, no mid-tile vm
// stall — the DMA has the whole tile to complete before the barrier drain).
// S^T = K·Q^T (softmax stats per-column, q = lane&15); P stays in registers;
// PV = 16x16x32 MFMA with permuted k-map, B-fragment = single b128 read.
// ---------------------------------------------------------------------------
__global__ __launch_bounds__(512, 2) void fa_mfma(
    const float* __restrict__ q,
    const uint16_t* __restrict__ kb,
    const uint16_t* __restrict__ vt,
    float* __restrict__ out)
{
    const int tid  = threadIdx.x;
    const int wave = tid >> 6;             // 0..7
    const int lane = tid & 63;
    const int l4   = lane >> 4;
    const int l15  = lane & 15;

    const int bh   = blockIdx.x >> 4;      // b*NH + h
    const int qblk = blockIdx.x & 15;
    const int q0   = qblk << 7;            // 128 queries per block
    const int hkv  = (bh & (NH - 1)) >> 2; // G = 4
    const int b    = bh >> 4;

    const int i0   = q0 + wave * 16;       // wave's first query row

    __shared__ __align__(16) uint16_t lds_k[2][64 * HD];
    __shared__ __align__(16) uint16_t lds_vt[2][64 * HD];

    // scale * log2(e): softmax computed in exp2 domain
    const float scale2 = 0.08838834764831845f * 1.4426950408889634f;

    const size_t qbase = (size_t)bh * SEQ * HD;
    const uint16_t* kt_base = kb + (size_t)(b * NKV + hkv) * SEQ * HD;
    const uint16_t* vt_base = vt + (size_t)(b * NKV + hkv) * SEQ * HD;

    // ---- preload Q fragments (B-operand: B[k=dim][n=q], q = l15) ----
    bf16x8 qf[4];
    {
        const float* qr = q + qbase + (size_t)(i0 + l15) * HD;
        #pragma unroll
        for (int ks = 0; ks < 4; ++ks) {
            const float4* g = reinterpret_cast<const float4*>(qr + ks * 32 + l4 * 8);
            float4 a = g[0], bq = g[1];
            u32x4 t;
            t.x = pk2(a.x * scale2, a.y * scale2);
            t.y = pk2(a.z * scale2, a.w * scale2);
            t.z = pk2(bq.x * scale2, bq.y * scale2);
            t.w = pk2(bq.z * scale2, bq.w * scale2);
            qf[ks] = __builtin_bit_cast(bf16x8, t);
        }
    }

    f32x4 O[8];
    #pragma unroll
    for (int a2 = 0; a2 < 8; ++a2) O[a2] = (f32x4){0.f, 0.f, 0.f, 0.f};
    float mrow = -1e30f;
    float lrow = 0.f;

    const int kt_lo_blk = (q0 >= 512) ? ((q0 - 511) >> 6) : 0;
    const int kt_hi_blk = (q0 + 127) >> 6;
    const int lo_w = (i0 >= 512) ? ((i0 - 511) >> 6) : 0;
    const int hi_w = (i0 + 15) >> 6;

    // ---- DMA staging: 2x16B K + 2x16B V per thread per tile ----
    auto stage = [&](int kt, int pb) {
        const uint16_t* ks = kt_base + (size_t)kt * 64 * HD;
        const uint16_t* vs = vt_base + (size_t)kt * 64 * HD;
        const int ch = wave * 2;
        #pragma unroll
        for (int c = 0; c < 2; ++c) {
            __builtin_amdgcn_global_load_lds(
                AS1(ks + (ch + c) * 512 + lane * 8),
                AS3(&lds_k[pb][(ch + c) * 512]), 16, 0, 0);
            __builtin_amdgcn_global_load_lds(
                AS1(vs + (ch + c) * 512 + lane * 8),
                AS3(&lds_vt[pb][(ch + c) * 512]), 16, 0, 0);
        }
    };

    stage(kt_lo_blk, 0);
    __syncthreads();   // drains vmcnt -> buffer 0 ready

    int par = 0;
    for (int kt = kt_lo_blk; kt <= kt_hi_blk; ++kt) {
        if (kt < kt_hi_blk) stage(kt + 1, par ^ 1);  // fire-and-forget DMA

        if (kt >= lo_w && kt <= hi_w) {
            // ---------- S^T = K · Q^T (16 MFMAs, K=32; swizzled reads) ------
            f32x4 sf[4];
            #pragma unroll
            for (int mt = 0; mt < 4; ++mt) sf[mt] = (f32x4){0.f, 0.f, 0.f, 0.f};
            __builtin_amdgcn_s_setprio(1);
            #pragma unroll
            for (int mt = 0; mt < 4; ++mt) {
                const int arow = mt * 16 + l15;
                #pragma unroll
                for (int ks = 0; ks < 4; ++ks) {
                    bf16x8 af = *reinterpret_cast<const bf16x8*>(
                        &lds_k[par][arow * HD + ((((ks * 4 + l4) ^ (arow & 7))) << 3)]);
                    sf[mt] = __builtin_amdgcn_mfma_f32_16x16x32_bf16(
                        af, qf[ks], sf[mt], 0, 0, 0);
                }
            }
            __builtin_amdgcn_s_setprio(0);
            // ---------- mask (first/window and last/causal tiles only) ------
            const bool needmask = (kt == hi_w) || (kt == lo_w && i0 > 511);
            if (needmask) {
                const int iq = i0 + l15;
                #pragma unroll
                for (int mt = 0; mt < 4; ++mt) {
                    int jb = kt * 64 + mt * 16 + l4 * 4;
                    #pragma unroll
                    for (int r = 0; r < 4; ++r) {
                        int j = jb + r;
                        if (!((j <= iq) && (iq - j < WIN))) sf[mt][r] = -1e30f;
                    }
                }
            }
            // ---------- online softmax, exp2 domain, defer-max (THR=8) ------
            float a0 = fmaxf(fmaxf(sf[0][0], sf[0][1]), fmaxf(sf[0][2], sf[0][3]));
            float a1 = fmaxf(fmaxf(sf[1][0], sf[1][1]), fmaxf(sf[1][2], sf[1][3]));
            float a2 = fmaxf(fmaxf(sf[2][0], sf[2][1]), fmaxf(sf[2][2], sf[2][3]));
            float a3 = fmaxf(fmaxf(sf[3][0], sf[3][1]), fmaxf(sf[3][2], sf[3][3]));
            float tm = fmaxf(fmaxf(a0, a1), fmaxf(a2, a3));
            tm = fmaxf(tm, __shfl_xor(tm, 16, 64));
            tm = fmaxf(tm, __shfl_xor(tm, 32, 64));
            const bool defer = __all(tm <= mrow + 8.0f);
            if (!defer) {
                float mn = fmaxf(mrow, tm);
                float alpha = EXP2(mrow - mn);
                mrow = mn;
                lrow *= alpha;
                #pragma unroll
                for (int r = 0; r < 4; ++r) {
                    float ar = __shfl(alpha, l4 * 4 + r, 64);
                    #pragma unroll
                    for (int nt = 0; nt < 8; ++nt) O[nt][r] *= ar;
                }
            }
            // ---------- P in registers (bf16 pairs), per-column sums --------
            bf16x4 pfrag[4];
            {
                float me = fmaxf(mrow, -1e20f);   // fully-masked rows -> p = 0
                float s[4];
                #pragma unroll
                for (int mt = 0; mt < 4; ++mt) {
                    float p0 = EXP2(sf[mt][0] - me);
                    float p1 = EXP2(sf[mt][1] - me);
                    float p2 = EXP2(sf[mt][2] - me);
                    float p3 = EXP2(sf[mt][3] - me);
                    u32x2 t;
                    t.x = pk2(p0, p1);
                    t.y = pk2(p2, p3);
                    pfrag[mt] = __builtin_bit_cast(bf16x4, t);
                    s[mt] = (p0 + p1) + (p2 + p3);
                }
                float ts = (s[0] + s[1]) + (s[2] + s[3]);
                ts += __shfl_xor(ts, 16, 64);
                ts += __shfl_xor(ts, 32, 64);
                lrow += ts;
            }
            // ---------- O += P · V  (16 MFMAs, K=32, permuted k-map) --------
            // B slot j at group l4 <-> key s*32 + (j>>2)*16 + l4*4 + (j&3),
            // matching pa = concat(pfrag[2s], pfrag[2s+1]); V^T key-perm makes
            // the B-fragment one contiguous (swizzled) b128.
            __builtin_amdgcn_s_setprio(1);
            #pragma unroll
            for (int s = 0; s < 2; ++s) {
                bf16x8 pa = __builtin_shufflevector(pfrag[2 * s], pfrag[2 * s + 1],
                                                    0, 1, 2, 3, 4, 5, 6, 7);
                #pragma unroll
                for (int nt = 0; nt < 8; ++nt) {
                    const int vr = nt * 16 + l15;
                    bf16x8 vf = *reinterpret_cast<const bf16x8*>(
                        &lds_vt[par][vr * 64 + ((((s * 4 + l4) ^ (vr & 7))) << 3)]);
                    O[nt] = __builtin_amdgcn_mfma_f32_16x16x32_bf16(pa, vf, O[nt], 0, 0, 0);
                }
            }
            __builtin_amdgcn_s_setprio(0);
        }
        __syncthreads();   // all reads of par done + next-tile DMA drained
        par ^= 1;
    }

    // ---------- epilogue: O / l, f32 out ----------
    {
        float inv = 1.0f / lrow;
        #pragma unroll
        for (int r = 0; r < 4; ++r) {
            float li = __shfl(inv, l4 * 4 + r, 64);
            int row = i0 + l4 * 4 + r;
            float* orow = out + qbase + (size_t)row * HD;
            #pragma unroll
            for (int nt = 0; nt < 8; ++nt)
                orow[nt * 16 + l15] = O[nt][r] * li;
        }
    }
}

// ---------------------------------------------------------------------------
// Fallback (round-6 fused kernel, verbatim): used only if d_ws is too small
// for the 8 MB prep workspace, so the submission never writes out-of-bounds.
// ---------------------------------------------------------------------------
#define KSTR 136
#define VSTR 72
#define VT_ROWS (HD * VSTR + (HD / 4) * 4)
__device__ __forceinline__ int vt_off(int row, int col) {
    return row * VSTR + (row >> 2) * 4 + col;
}

__global__ __launch_bounds__(512, 2)
void fa_mfma_fused(
    const float* __restrict__ q,
    const float* __restrict__ k,
    const float* __restrict__ v,
    float* __restrict__ out)
{
    const int tid  = threadIdx.x;
    const int wave = tid >> 6;
    const int lane = tid & 63;
    const int l4   = lane >> 4;
    const int l15  = lane & 15;

    const int bh   = blockIdx.x >> 4;
    const int qblk = blockIdx.x & 15;
    const int q0   = qblk << 7;
    const int hkv  = (bh & (NH - 1)) >> 2;
    const int b    = bh >> 4;

    const int i0   = q0 + wave * 16;

    __shared__ __align__(16) uint16_t lds_k[2][64 * KSTR];
    __shared__ __align__(16) uint16_t lds_vt[2][VT_ROWS];

    const float scale2 = 0.08838834764831845f * 1.4426950408889634f;

    const size_t qbase  = (size_t)bh * SEQ * HD;
    const size_t kvbase = (size_t)(b * NKV + hkv) * SEQ * HD;

    bf16x8 qf[4];
    {
        const float* qr = q + qbase + (size_t)(i0 + l15) * HD;
        #pragma unroll
        for (int ks = 0; ks < 4; ++ks) {
            const float4* g = reinterpret_cast<const float4*>(qr + ks * 32 + l4 * 8);
            float4 a = g[0], bq = g[1];
            u32x4 t;
            t.x = pk2(a.x * scale2, a.y * scale2);
            t.y = pk2(a.z * scale2, a.w * scale2);
            t.z = pk2(bq.x * scale2, bq.y * scale2);
            t.w = pk2(bq.z * scale2, bq.w * scale2);
            qf[ks] = __builtin_bit_cast(bf16x8, t);
        }
    }

    f32x4 O[8];
    #pragma unroll
    for (int a2 = 0; a2 < 8; ++a2) O[a2] = (f32x4){0.f, 0.f, 0.f, 0.f};
    float mrow = -1e30f;
    float lrow = 0.f;

    const int kt_lo_blk = (q0 >= 512) ? ((q0 - 511) >> 6) : 0;
    const int kt_hi_blk = (q0 + 127) >> 6;
    const int lo_w = (i0 >= 512) ? ((i0 - 511) >> 6) : 0;
    const int hi_w = (i0 + 15) >> 6;

    const int vdg = tid & 31;
    const int vkg = tid >> 5;
    float4 rKa[2], rKb[2], rV[4];

    auto prefetch_k = [&](int kt) {
        const float* kp = k + kvbase + (size_t)kt * 64 * HD;
        #pragma unroll
        for (int it = 0; it < 2; ++it) {
            int flat8 = tid + it * 512, key = flat8 >> 4, ch = flat8 & 15;
            const float4* g = reinterpret_cast<const float4*>(kp + key * HD + ch * 8);
            rKa[it] = g[0]; rKb[it] = g[1];
        }
    };
    auto prefetch_v = [&](int kt) {
        const float* vp = v + kvbase + (size_t)kt * 64 * HD;
        #pragma unroll
        for (int r = 0; r < 4; ++r)
            rV[r] = *reinterpret_cast<const float4*>(vp + (vkg * 4 + r) * HD + vdg * 4);
    };
    auto pack_k = [&](int pb) {
        #pragma unroll
        for (int it = 0; it < 2; ++it) {
            int flat8 = tid + it * 512, key = flat8 >> 4, ch = flat8 & 15;
            uint4 wv;
            wv.x = pk2(rKa[it].x, rKa[it].y);  wv.y = pk2(rKa[it].z, rKa[it].w);
            wv.z = pk2(rKb[it].x, rKb[it].y);  wv.w = pk2(rKb[it].z, rKb[it].w);
            *reinterpret_cast<uint4*>(&lds_k[pb][key * KSTR + ch * 8]) = wv;
        }
    };
    auto pack_v = [&](int pb) {
        const float* rvf = reinterpret_cast<const float*>(rV);
        #pragma unroll
        for (int i = 0; i < 4; ++i) {
            u32x2 wv;
            wv.x = pk2(rvf[0 * 4 + i], rvf[1 * 4 + i]);
            wv.y = pk2(rvf[2 * 4 + i], rvf[3 * 4 + i]);
            *reinterpret_cast<u32x2*>(&lds_vt[pb][vt_off(vdg * 4 + i, vkg * 4)]) = wv;
        }
    };

    prefetch_k(kt_lo_blk);
    prefetch_v(kt_lo_blk);
    pack_k(0);
    pack_v(0);
    __syncthreads();

    int par = 0;
    for (int kt = kt_lo_blk; kt <= kt_hi_blk; ++kt) {
        const bool more = (kt < kt_hi_blk);
        if (more) prefetch_k(kt + 1);

        if (kt >= lo_w && kt <= hi_w) {
            f32x4 sf[4];
            #pragma unroll
            for (int mt = 0; mt < 4; ++mt) sf[mt] = (f32x4){0.f, 0.f, 0.f, 0.f};
            __builtin_amdgcn_s_setprio(1);
            #pragma unroll
            for (int mt = 0; mt < 4; ++mt) {
                #pragma unroll
                for (int ks = 0; ks < 4; ++ks) {
                    bf16x8 af = *reinterpret_cast<const bf16x8*>(
                        &lds_k[par][(mt * 16 + l15) * KSTR + ks * 32 + l4 * 8]);
                    sf[mt] = __builtin_amdgcn_mfma_f32_16x16x32_bf16(
                        af, qf[ks], sf[mt], 0, 0, 0);
                }
            }
            __builtin_amdgcn_s_setprio(0);
            if (more) { pack_k(par ^ 1); prefetch_v(kt + 1); }
            const bool needmask = (kt == hi_w) || (kt == lo_w && i0 > 511);
            if (needmask) {
                const int iq = i0 + l15;
                #pragma unroll
                for (int mt = 0; mt < 4; ++mt) {
                    int jb = kt * 64 + mt * 16 + l4 * 4;
                    #pragma unroll
                    for (int r = 0; r < 4; ++r) {
                        int j = jb + r;
                        if (!((j <= iq) && (iq - j < WIN))) sf[mt][r] = -1e30f;
                    }
                }
            }
            float a0 = fmaxf(fmaxf(sf[0][0], sf[0][1]), fmaxf(sf[0][2], sf[0][3]));
            float a1 = fmaxf(fmaxf(sf[1][0], sf[1][1]), fmaxf(sf[1][2], sf[1][3]));
            float a2 = fmaxf(fmaxf(sf[2][0], sf[2][1]), fmaxf(sf[2][2], sf[2][3]));
            float a3 = fmaxf(fmaxf(sf[3][0], sf[3][1]), fmaxf(sf[3][2], sf[3][3]));
            float tm = fmaxf(fmaxf(a0, a1), fmaxf(a2, a3));
            tm = fmaxf(tm, __shfl_xor(tm, 16, 64));
            tm = fmaxf(tm, __shfl_xor(tm, 32, 64));
            const bool defer = __all(tm <= mrow + 8.0f);
            if (!defer) {
                float mn = fmaxf(mrow, tm);
                float alpha = EXP2(mrow - mn);
                mrow = mn;
                lrow *= alpha;
                #pragma unroll
                for (int r = 0; r < 4; ++r) {
                    float ar = __shfl(alpha, l4 * 4 + r, 64);
                    #pragma unroll
                    for (int nt = 0; nt < 8; ++nt) O[nt][r] *= ar;
                }
            }
            bf16x4 pfrag[4];
            {
                float me = fmaxf(mrow, -1e20f);
                float s[4];
                #pragma unroll
                for (int mt = 0; mt < 4; ++mt) {
                    float p0 = EXP2(sf[mt][0] - me);
                    float p1 = EXP2(sf[mt][1] - me);
                    float p2 = EXP2(sf[mt][2] - me);
                    float p3 = EXP2(sf[mt][3] - me);
                    u32x2 t;
                    t.x = pk2(p0, p1);
                    t.y = pk2(p2, p3);
                    pfrag[mt] = __builtin_bit_cast(bf16x4, t);
                    s[mt] = (p0 + p1) + (p2 + p3);
                }
                float ts = (s[0] + s[1]) + (s[2] + s[3]);
                ts += __shfl_xor(ts, 16, 64);
                ts += __shfl_xor(ts, 32, 64);
                lrow += ts;
            }
            if (more) pack_v(par ^ 1);
            __builtin_amdgcn_s_setprio(1);
            #pragma unroll
            for (int s = 0; s < 2; ++s) {
                bf16x8 pa = __builtin_shufflevector(pfrag[2 * s], pfrag[2 * s + 1],
                                                    0, 1, 2, 3, 4, 5, 6, 7);
                #pragma unroll
                for (int nt = 0; nt < 8; ++nt) {
                    const int vr = nt * 16 + l15;
                    bf16x4 v0 = *reinterpret_cast<const bf16x4*>(
                        &lds_vt[par][vt_off(vr, s * 32 + l4 * 4)]);
                    bf16x4 v1 = *reinterpret_cast<const bf16x4*>(
                        &lds_vt[par][vt_off(vr, s * 32 + 16 + l4 * 4)]);
                    bf16x8 vf = __builtin_shufflevector(v0, v1, 0, 1, 2, 3, 4, 5, 6, 7);
                    O[nt] = __builtin_amdgcn_mfma_f32_16x16x32_bf16(pa, vf, O[nt], 0, 0, 0);
                }
            }
            __builtin_amdgcn_s_setprio(0);
        } else {
            if (more) { prefetch_v(kt + 1); pack_k(par ^ 1); pack_v(par ^ 1); }
        }
        __syncthreads();
        par ^= 1;
    }

    {
        float inv = 1.0f / lrow;
        #pragma unroll
        for (int r = 0; r < 4; ++r) {
            float li = __shfl(inv, l4 * 4 + r, 64);
            int row = i0 + l4 * 4 + r;
            float* orow = out + qbase + (size_t)row * HD;
            #pragma unroll
            for (int nt = 0; nt < 8; ++nt)
                orow[nt * 16 + l15] = O[nt][r] * li;
        }
    }
}

extern "C" void kernel_launch(void* const* d_in, const int* in_sizes, int n_in,
                              void* d_out, int out_size, void* d_ws, size_t ws_size,
                              hipStream_t stream) {
    const float* q = (const float*)d_in[0];
    const float* k = (const float*)d_in[1];
    const float* v = (const float*)d_in[2];
    float* out     = (float*)d_out;

    const size_t kv_elems = (size_t)BATCH * NKV * SEQ * HD;   // 2,097,152
    const size_t ws_needed = kv_elems * 2u * sizeof(uint16_t); // 8 MB

    if (d_ws != nullptr && ws_size >= ws_needed) {
        uint16_t* kb  = (uint16_t*)d_ws;           // 4 MB
        uint16_t* vtw = kb + kv_elems;             // 4 MB
        hipLaunchKernelGGL(prep_kv, dim3(BATCH * NKV * (SEQ / 64)), dim3(256), 0,
                           stream, k, v, kb, vtw);
        hipLaunchKernelGGL(fa_mfma, dim3(BATCH * NH * (SEQ / 128)), dim3(512), 0,
                           stream, q, kb, vtw, out);
    } else {
        hipLaunchKernelGGL(fa_mfma_fused, dim3(BATCH * NH * (SEQ / 128)), dim3(512),
                           0, stream, q, k, v, out);
    }
}